// Round 8
// baseline (1419.721 us; speedup 1.0000x reference)
//
#include <hip/hip_runtime.h>
#include <hip/hip_bf16.h>
#include <math.h>

typedef __bf16 bf16;
typedef __bf16 bf16x8 __attribute__((ext_vector_type(8)));
typedef __bf16 bf16x4 __attribute__((ext_vector_type(4)));
typedef short  s16x4  __attribute__((ext_vector_type(4)));
typedef float  f32x4  __attribute__((ext_vector_type(4)));

#define MFMA32(a,b,c) __builtin_amdgcn_mfma_f32_16x16x32_bf16((a),(b),(c),0,0,0)
#define MFMA16(a,b,c) __builtin_amdgcn_mfma_f32_16x16x16bf16_1k((a),(b),(c),0,0,0)
#define EXP2F(x) __builtin_amdgcn_exp2f(x)
// async global->LDS, 16B per lane; LDS dest is wave-uniform base + lane*16 (m104/m108)
#define GLL16(gp, lp) __builtin_amdgcn_global_load_lds(\
    (const __attribute__((address_space(1))) void*)(gp), \
    (__attribute__((address_space(3))) void*)(lp), 16, 0, 0)

__device__ __forceinline__ float wave_sum(float v){
#pragma unroll
  for(int off=1; off<64; off<<=1) v += __shfl_xor(v, off);
  return v;
}

// ---------------- fused (add) + layernorm -> bf16 ----------------
__global__ __launch_bounds__(256) void add_ln_kernel(
    const float* __restrict__ xsrc, const float* __restrict__ addsrc,
    const float* __restrict__ emb,
    const float* __restrict__ gw, const float* __restrict__ gb,
    float* __restrict__ xout, bf16* __restrict__ hout)
{
  const int row = blockIdx.x;
  const int t = threadIdx.x;
  const size_t rbase = (size_t)row * 1024;
  float4 x = ((const float4*)(xsrc + rbase))[t];
  if(addsrc){
    float4 a = ((const float4*)(addsrc + rbase))[t];
    x.x += a.x; x.y += a.y; x.z += a.z; x.w += a.w;
  }
  if(emb){
    float4 e = ((const float4*)emb)[t];
    x.x += e.x; x.y += e.y; x.z += e.z; x.w += e.w;
  }
  if(xout) ((float4*)(xout + rbase))[t] = x;

  float s = x.x + x.y + x.z + x.w;
  float q = x.x*x.x + x.y*x.y + x.z*x.z + x.w*x.w;
  s = wave_sum(s); q = wave_sum(q);
  __shared__ float red[8];
  const int w = t >> 6;
  if((t & 63) == 0){ red[w] = s; red[4+w] = q; }
  __syncthreads();
  s = red[0]+red[1]+red[2]+red[3];
  q = red[4]+red[5]+red[6]+red[7];
  const float mean = s * (1.0f/1024.0f);
  const float var  = q * (1.0f/1024.0f) - mean*mean;
  const float inv  = rsqrtf(var + 1e-5f);

  float4 wv = ((const float4*)gw)[t];
  float4 bv = ((const float4*)gb)[t];
  bf16x4 hv;
  hv[0] = (bf16)((x.x - mean)*inv*wv.x + bv.x);
  hv[1] = (bf16)((x.y - mean)*inv*wv.y + bv.y);
  hv[2] = (bf16)((x.z - mean)*inv*wv.z + bv.z);
  hv[3] = (bf16)((x.w - mean)*inv*wv.w + bv.w);
  *(bf16x4*)(hout + rbase + t*4) = hv;
}

// ---------------- weight packing ----------------
__global__ __launch_bounds__(256) void pack_qkv3_kernel(
    const float* __restrict__ Wq, const float* __restrict__ Wk, const float* __restrict__ Wv,
    bf16* __restrict__ Wt)
{
  const int i = blockIdx.x*256 + threadIdx.x;       // 0..3M
  const int seg = i >> 20, j = i & 1048575;
  const float* W = (seg==0) ? Wq : (seg==1 ? Wk : Wv);
  const int n = j >> 10, d = j & 1023;
  const int h = n >> 6, kk = n & 63;
  Wt[i] = (bf16)W[h*65536 + d*64 + kk];
}
__global__ __launch_bounds__(256) void pack_t_kernel(const float* __restrict__ W, bf16* __restrict__ Wt, int Kd, int Nd){
  const int i = blockIdx.x*256 + threadIdx.x;
  const int n = i / Kd, k = i - n*Kd;
  Wt[i] = (bf16)W[(size_t)k*Nd + n];
}
__global__ __launch_bounds__(256) void pack_cast_kernel(const float* __restrict__ W, bf16* __restrict__ Wb){
  const int i = blockIdx.x*256 + threadIdx.x;
  Wb[i] = (bf16)W[i];
}
__global__ __launch_bounds__(256) void biasmv_kernel(const float* __restrict__ bin, const bf16* __restrict__ WT,
                                                     const float* __restrict__ badd, float* __restrict__ out, int Kd){
  const int n = blockIdx.x, t = threadIdx.x;
  float acc = 0.f;
  for(int k=t; k<Kd; k+=256) acc += bin[k]*(float)WT[(size_t)n*Kd + k];
  acc = wave_sum(acc);
  __shared__ float red[4];
  if((t&63)==0) red[t>>6] = acc;
  __syncthreads();
  if(t==0) out[n] = red[0]+red[1]+red[2]+red[3] + badd[n];
}

// ---------------- bf16 MFMA GEMM, BK=64:  C[M,N] = A[M,K] * Bt[N,K]^T ----------------
// EPI: 0 plain->bf16 ; 1 +bias->bf16 ; 2 res+acc+bias->f32 ; 3 res+gelu(acc+bias)->f32 ;
//      4 qkv split (q prescaled by log2e/32, v transposed per-head) ;
//      5 cur' = res2 + res + gelu(acc+bias) + embn[col]
template<int EPI, int BLKM>
__global__ __launch_bounds__(256,2) void gemm_kernel(
    const bf16* __restrict__ A, const bf16* __restrict__ Bt,
    float* __restrict__ outf, bf16* __restrict__ outb,
    bf16* __restrict__ o2, bf16* __restrict__ o3,
    const float* __restrict__ bias, const float* __restrict__ res,
    const float* __restrict__ res2, const float* __restrict__ embn,
    int N, int K)
{
  constexpr int RM = BLKM/32;
  constexpr int HM = BLKM/2;
  constexpr int AISS = BLKM/32;
  __shared__ __align__(16) bf16 As[BLKM*64];
  __shared__ __align__(16) bf16 Bs[128*64];
  const int tid = threadIdx.x, w = tid>>6, lane = tid&63;
  const int quad = lane>>4, l16 = lane&15;
  const int wm = w&1, wn = w>>1;
  const int tn = blockIdx.x, tm = blockIdx.y;

  const int srow = lane>>3;
  const int sch  = (lane&7) ^ srow;
  const bf16* Ag = A  + (size_t)(tm*BLKM + w*8 + srow)*K + sch*8;
  const bf16* Bg = Bt + (size_t)(tn*128  + w*8 + srow)*K + sch*8;

  f32x4 acc[RM][4] = {};

  for(int k0 = 0; k0 < K; k0 += 64){
#pragma unroll
    for(int i=0;i<AISS;i++) GLL16(Ag + (size_t)(i*32)*K, As + (w*8 + i*32)*64);
#pragma unroll
    for(int i=0;i<4;i++)    GLL16(Bg + (size_t)(i*32)*K, Bs + (w*8 + i*32)*64);
    Ag += 64; Bg += 64;
    __syncthreads();
    bf16x8 af[RM][2], bfr[4][2];
#pragma unroll
    for(int r=0;r<RM;r++){
      const int row = wm*HM + r*16 + l16;
      const bf16* rp = As + row*64;
#pragma unroll
      for(int kc=0;kc<2;kc++)
        af[r][kc] = *(const bf16x8*)(rp + ((kc*4+quad) ^ (row&7))*8);
    }
#pragma unroll
    for(int c=0;c<4;c++){
      const int row = wn*64 + c*16 + l16;
      const bf16* rp = Bs + row*64;
#pragma unroll
      for(int kc=0;kc<2;kc++)
        bfr[c][kc] = *(const bf16x8*)(rp + ((kc*4+quad) ^ (row&7))*8);
    }
#pragma unroll
    for(int kc=0;kc<2;kc++)
#pragma unroll
      for(int r=0;r<RM;r++)
#pragma unroll
        for(int c=0;c<4;c++)
          acc[r][c] = MFMA32(af[r][kc], bfr[c][kc], acc[r][c]);
    __syncthreads();
  }

  // C/D: col = lane&15, row = quad*4 + reg
#pragma unroll
  for(int r=0;r<RM;r++){
    const int grow0 = tm*BLKM + wm*HM + r*16 + quad*4;
#pragma unroll
    for(int c=0;c<4;c++){
      const int gcol = tn*128 + wn*64 + c*16 + l16;
      float bv = 0.0f;
      if constexpr (EPI>=1 && EPI!=4) bv = bias[gcol];
      if constexpr (EPI==4){
        const int seg = gcol >> 10;          // wave-uniform
        if(seg < 2){
          bf16* op = (seg==0) ? outb : o2;
          // q: fold 1024^-0.5 * log2(e) so attention uses raw v_exp_f32 (exp2)
          const float qs = (seg==0) ? 0.045084439f : 1.0f;
          const int col = gcol & 1023;
#pragma unroll
          for(int g=0; g<4; g++)
            op[(size_t)(grow0+g)*1024 + col] = (bf16)(acc[r][c][g]*qs);
        } else {
          const int col0 = gcol & 1023, hh = col0>>6, kk = col0&63;
          const int btok = grow0>>10, t0 = grow0&1023;
          bf16x4 pv;
#pragma unroll
          for(int g=0; g<4; g++) pv[g] = (bf16)acc[r][c][g];
          *(bf16x4*)(o3 + ((size_t)(btok*16+hh)*64 + kk)*1024 + t0) = pv;
        }
      } else {
        const float ev = (EPI==5) ? embn[gcol] : 0.0f;
#pragma unroll
        for(int g=0; g<4; g++){
          const float vv = acc[r][c][g] + bv;
          const size_t idx = (size_t)(grow0+g)*N + gcol;
          if constexpr (EPI<=1){
            outb[idx] = (bf16)vv;
          } else if constexpr (EPI==2){
            outf[idx] = res[idx] + vv;
          } else if constexpr (EPI==3){
            const float gel = 0.5f*vv*(1.0f + erff(vv*0.70710678118654752f));
            outf[idx] = res[idx] + gel;
          } else {
            const float gel = 0.5f*vv*(1.0f + erff(vv*0.70710678118654752f));
            outf[idx] = res[idx] + gel + res2[idx] + ev;
          }
        }
      }
    }
  }
}

// ---------------- fused causal attention: parity split-K + clean/diag paths ----------------
// grid (64 bh, 8 p, 2 s): block handles q-tiles A=p, B=15-p with keys kb ≡ s (mod 2)
// -> 1024 blocks = 4 blocks/CU (vs 2), ~8.5 tile-iters each (balanced).
// No-max softmax makes split-K merging additive: O = (O0+O1)/(l0+l1) (merge kernel).
// Clean iterations (non-diag, >=80%) run with constant nc=4 and ZERO mask VALU;
// exp via raw v_exp_f32 (exp2) — scale*log2(e) folded into Q at the QKV epilogue.
constexpr int LDK = 72;   // padded rows: 2-way bank alias only (free)

__global__ __launch_bounds__(256) void attn_kernel(
    const bf16* __restrict__ Q, const bf16* __restrict__ Km,
    const bf16* __restrict__ Vt, bf16* __restrict__ pO, float* __restrict__ pL)
{
  __shared__ __align__(16) bf16 Ks[2][64*LDK];   // [buf][key][hd]
  __shared__ __align__(16) bf16 Vs[2][64*LDK];   // [buf][hd][key]
  const int p  = blockIdx.y, sp = blockIdx.z;    // parity
  const int qtA = p, qtB = 15 - p;
  const int bh = blockIdx.x;                     // XCD = bh%8
  const int b = bh >> 4, h = bh & 15;
  const int tid = threadIdx.x;
  const int w = tid>>6, lane = tid&63, quad = lane>>4, l16 = lane&15;
  const size_t qbase = (size_t)b*1024*1024 + (size_t)h*64;
  const size_t vbase = (size_t)(bh*64)*1024;
  const int qrowA0 = qtA*64 + w*16, qrowB0 = qtB*64 + w*16;
  const int myrowA = qrowA0 + l16,  myrowB = qrowB0 + l16;

  const bf16* qpA = Q + qbase + (size_t)myrowA*1024 + quad*8;
  const bf16* qpB = Q + qbase + (size_t)myrowB*1024 + quad*8;
  bf16x8 bqA0 = *(const bf16x8*)qpA, bqA1 = *(const bf16x8*)(qpA + 32);
  bf16x8 bqB0 = *(const bf16x8*)qpB, bqB1 = *(const bf16x8*)(qpB + 32);

  f32x4 oA[4] = {}, oB[4] = {};     // O^T: hd = d*16+quad*4+g, qrow = l16
  float lA = 0.f, lB = 0.f;
  const f32x4 zf = {0.f,0.f,0.f,0.f};

  const int r0 = tid>>3, c0 = (tid&7)*8;
  const bf16* kg = Km + qbase + c0;
  const bf16* vg = Vt + vbase + (size_t)r0*1024 + c0;

  // prologue: stage kb=sp into buffer 0
  {
    const bf16* kgp = kg + (size_t)(sp*64 + r0)*1024;
    bf16x8 a0 = *(const bf16x8*)kgp;
    bf16x8 a1 = *(const bf16x8*)(kgp + (size_t)32*1024);
    const bf16* vgp = vg + sp*64;
    bf16x8 v0 = *(const bf16x8*)vgp;
    bf16x8 v1 = *(const bf16x8*)(vgp + (size_t)32*1024);
    *(bf16x8*)(Ks[0] + r0*LDK + c0)      = a0;
    *(bf16x8*)(Ks[0] + (r0+32)*LDK + c0) = a1;
    *(bf16x8*)(Vs[0] + r0*LDK + c0)      = v0;
    *(bf16x8*)(Vs[0] + (r0+32)*LDK + c0) = v1;
  }

  int bi = 0;
  for(int kb = sp; kb <= qtB; kb += 2){
    __syncthreads();                       // staging of kb visible; old reads done
    const bool pf = (kb+2 <= qtB);
    bf16x8 nk0, nk1, nv0, nv1;
    if(pf){
      const bf16* kgp = kg + (size_t)((kb+2)*64 + r0)*1024;
      nk0 = *(const bf16x8*)kgp;
      nk1 = *(const bf16x8*)(kgp + (size_t)32*1024);
      const bf16* vgp = vg + (kb+2)*64;
      nv0 = *(const bf16x8*)vgp;
      nv1 = *(const bf16x8*)(vgp + (size_t)32*1024);
    }

    const bool diagA = (kb == qtA), diagB = (kb == qtB);
    const bool doA = (kb <= qtA);
    const bf16* ksb = Ks[bi];
    const bf16* vsb = Vs[bi];

    if(!(diagA | diagB)){
      // ---------- clean path: no masks, constant tile counts ----------
      f32x4 sB4[4], sA4[4];
#pragma unroll
      for(int c=0;c<4;c++){
        bf16x8 ak0 = *(const bf16x8*)(ksb + (c*16+l16)*LDK + quad*8);
        bf16x8 ak1 = *(const bf16x8*)(ksb + (c*16+l16)*LDK + 32 + quad*8);
        sB4[c] = MFMA32(ak0, bqB0, zf);
        sB4[c] = MFMA32(ak1, bqB1, sB4[c]);
        if(doA){
          sA4[c] = MFMA32(ak0, bqA0, zf);
          sA4[c] = MFMA32(ak1, bqA1, sA4[c]);
        }
      }
      s16x4 pB[4], pA[4];
      {
        float rs = 0.f;
#pragma unroll
        for(int c=0;c<4;c++){
          bf16x4 pb;
#pragma unroll
          for(int g=0;g<4;g++){ const float e = EXP2F(sB4[c][g]); rs += e; pb[g] = (bf16)e; }
          pB[c] = __builtin_bit_cast(s16x4, pb);
        }
        rs += __shfl_xor(rs, 16); rs += __shfl_xor(rs, 32);
        lB += rs;
      }
      if(doA){
        float rs = 0.f;
#pragma unroll
        for(int c=0;c<4;c++){
          bf16x4 pb;
#pragma unroll
          for(int g=0;g<4;g++){ const float e = EXP2F(sA4[c][g]); rs += e; pb[g] = (bf16)e; }
          pA[c] = __builtin_bit_cast(s16x4, pb);
        }
        rs += __shfl_xor(rs, 16); rs += __shfl_xor(rs, 32);
        lA += rs;
      }
#pragma unroll
      for(int c=0;c<4;c++){
#pragma unroll
        for(int d=0;d<4;d++){
          bf16x4 av = *(const bf16x4*)(vsb + (d*16+l16)*LDK + c*16 + quad*4);
          const s16x4 avs = __builtin_bit_cast(s16x4, av);
          oB[d] = MFMA16(avs, pB[c], oB[d]);
          if(doA) oA[d] = MFMA16(avs, pA[c], oA[d]);
        }
      }
    } else {
      // ---------- diag path (<=2 iters/block): masked ----------
      const int ncA = diagA ? (w+1) : 0;
      const int ncB = diagB ? (w+1) : 4;
      f32x4 sA4[4], sB4[4];
#pragma unroll
      for(int c=0;c<4;c++){
        if(c >= ncB) continue;
        bf16x8 ak0 = *(const bf16x8*)(ksb + (c*16+l16)*LDK + quad*8);
        bf16x8 ak1 = *(const bf16x8*)(ksb + (c*16+l16)*LDK + 32 + quad*8);
        sB4[c] = MFMA32(ak0, bqB0, zf);
        sB4[c] = MFMA32(ak1, bqB1, sB4[c]);
        if(c < ncA){
          sA4[c] = MFMA32(ak0, bqA0, zf);
          sA4[c] = MFMA32(ak1, bqA1, sA4[c]);
        }
      }
      s16x4 pB[4], pA[4];
      {
        float rs = 0.f;
#pragma unroll
        for(int c=0;c<4;c++){
          if(c >= ncB) continue;
          bf16x4 pb;
#pragma unroll
          for(int g=0;g<4;g++){
            const int key = kb*64 + c*16 + quad*4 + g;
            const float e = (diagB && key > myrowB) ? 0.f : EXP2F(sB4[c][g]);
            rs += e; pb[g] = (bf16)e;
          }
          pB[c] = __builtin_bit_cast(s16x4, pb);
        }
        rs += __shfl_xor(rs, 16); rs += __shfl_xor(rs, 32);
        lB += rs;
      }
      if(ncA > 0){
        float rs = 0.f;
#pragma unroll
        for(int c=0;c<4;c++){
          if(c >= ncA) continue;
          bf16x4 pb;
#pragma unroll
          for(int g=0;g<4;g++){
            const int key = kb*64 + c*16 + quad*4 + g;
            const float e = (diagA && key > myrowA) ? 0.f : EXP2F(sA4[c][g]);
            rs += e; pb[g] = (bf16)e;
          }
          pA[c] = __builtin_bit_cast(s16x4, pb);
        }
        rs += __shfl_xor(rs, 16); rs += __shfl_xor(rs, 32);
        lA += rs;
      }
#pragma unroll
      for(int c=0;c<4;c++){
        if(c >= ncB) continue;
#pragma unroll
        for(int d=0;d<4;d++){
          bf16x4 av = *(const bf16x4*)(vsb + (d*16+l16)*LDK + c*16 + quad*4);
          const s16x4 avs = __builtin_bit_cast(s16x4, av);
          oB[d] = MFMA16(avs, pB[c], oB[d]);
          if(c < ncA) oA[d] = MFMA16(avs, pA[c], oA[d]);
        }
      }
    }

    // write prefetched kb+2 into the other buffer
    if(pf){
      bf16* kd = Ks[bi^1]; bf16* vd = Vs[bi^1];
      *(bf16x8*)(kd + r0*LDK + c0)      = nk0;
      *(bf16x8*)(kd + (r0+32)*LDK + c0) = nk1;
      *(bf16x8*)(vd + r0*LDK + c0)      = nv0;
      *(bf16x8*)(vd + (r0+32)*LDK + c0) = nv1;
    }
    bi ^= 1;
  }

  // epilogue: unnormalized bf16 partials, [s][bh][qt][qrow][hd]
  {
    const size_t ob = ((size_t)(sp*1024 + bh*16 + qtA)*64 + w*16 + l16)*64;
#pragma unroll
    for(int d=0;d<4;d++){
      bf16x4 pv;
#pragma unroll
      for(int g=0;g<4;g++) pv[g] = (bf16)oA[d][g];
      *(bf16x4*)(pO + ob + d*16 + quad*4) = pv;
    }
    if(lane < 16) pL[(size_t)(sp*1024 + bh*16 + qtA)*64 + w*16 + lane] = lA;
  }
  {
    const size_t ob = ((size_t)(sp*1024 + bh*16 + qtB)*64 + w*16 + l16)*64;
#pragma unroll
    for(int d=0;d<4;d++){
      bf16x4 pv;
#pragma unroll
      for(int g=0;g<4;g++) pv[g] = (bf16)oB[d][g];
      *(bf16x4*)(pO + ob + d*16 + quad*4) = pv;
    }
    if(lane < 16) pL[(size_t)(sp*1024 + bh*16 + qtB)*64 + w*16 + lane] = lB;
  }
}

// merge the two parity partials: O = (O0+O1)/(l0+l1); grid (64 bh, 16 qt) keeps bh%8 XCD locality
__global__ __launch_bounds__(256) void attn_merge_kernel(
    const bf16* __restrict__ pO, const float* __restrict__ pL, bf16* __restrict__ O)
{
  const int bh = blockIdx.x, qt = blockIdx.y;
  const int b = bh>>4, h = bh&15;
  const int t = threadIdx.x;
  const int hd0 = (t&15)*4;
  const size_t base0 = (size_t)(bh*16+qt)*4096;
  const size_t lb = (size_t)(bh*16+qt)*64;
#pragma unroll
  for(int i=0;i<4;i++){
    const int qrow = (t>>4) + i*16;
    const float inv = 1.0f/(pL[lb+qrow] + pL[lb+qrow+65536]);
    bf16x4 a = *(const bf16x4*)(pO + base0 + qrow*64 + hd0);
    bf16x4 c4 = *(const bf16x4*)(pO + base0 + 4194304 + qrow*64 + hd0);
    bf16x4 o;
#pragma unroll
    for(int g=0;g<4;g++) o[g] = (bf16)(((float)a[g]+(float)c4[g])*inv);
    *(bf16x4*)(O + (size_t)(b*1024 + qt*64 + qrow)*1024 + h*64 + hd0) = o;
  }
}

// ---------------- launch ----------------
extern "C" void kernel_launch(void* const* d_in, const int* in_sizes, int n_in,
                              void* d_out, int out_size, void* d_ws, size_t ws_size,
                              hipStream_t stream)
{
  const float* x_in = (const float*)d_in[0];
  const float* emb  = (const float*)d_in[1];
  const float* Wq   = (const float*)d_in[2];
  const float* Wk   = (const float*)d_in[3];
  const float* Wv   = (const float*)d_in[4];
  const float* fcw  = (const float*)d_in[5];
  const float* fcb  = (const float*)d_in[6];
  const float* ln1w = (const float*)d_in[7];
  const float* ln1b = (const float*)d_in[8];
  const float* ln2w = (const float*)d_in[9];
  const float* ln2b = (const float*)d_in[10];
  const float* w1   = (const float*)d_in[11];
  const float* b1   = (const float*)d_in[12];
  const float* w2   = (const float*)d_in[13];
  const float* b2   = (const float*)d_in[14];
  const float* w3   = (const float*)d_in[15];
  const float* b3   = (const float*)d_in[16];

  char* ws = (char*)d_ws;
  const size_t MB = 1024*1024;
  float* cur    = (float*)(ws + 0);
  float* x1     = (float*)(ws + 16*MB);
  bf16*  pO     = (bf16*)(ws + 32*MB);    // 16MB split-K partials [s][bh][qt][qrow][hd]
  bf16*  hb     = (bf16*)(ws + 48*MB);
  bf16*  attnb  = (bf16*)(ws + 56*MB);
  bf16*  qb     = (bf16*)(ws + 64*MB);
  bf16*  kbuf   = (bf16*)(ws + 72*MB);
  bf16*  vtb    = (bf16*)(ws + 80*MB);    // V^T per-head: [(b*16+h)*64+hd][t]
  bf16*  w1pl   = (bf16*)(ws + 88*MB);
  bf16*  T12    = (bf16*)(ws + 92*MB);
  bf16*  wqkvT  = (bf16*)(ws + 96*MB);
  bf16*  fcT    = (bf16*)(ws + 102*MB);
  bf16*  w2T    = (bf16*)(ws + 104*MB);
  bf16*  w3T    = (bf16*)(ws + 108*MB);
  bf16*  WeffT  = (bf16*)(ws + 110*MB);
  float* tmpb   = (float*)(ws + 112*MB);
  float* beff   = (float*)(ws + 112*MB + 8192);
  float* pL     = (float*)(ws + 112*MB + 16384);   // 512KB split-K l partials

  pack_qkv3_kernel<<<12288,256,0,stream>>>(Wq, Wk, Wv, wqkvT);
  pack_t_kernel<<<4096,256,0,stream>>>(fcw, fcT, 1024, 1024);
  pack_t_kernel<<<8192,256,0,stream>>>(w2,  w2T, 2048, 1024);
  pack_t_kernel<<<4096,256,0,stream>>>(w3,  w3T, 1024, 1024);
  pack_cast_kernel<<<8192,256,0,stream>>>(w1, w1pl);
  gemm_kernel<0,64><<<dim3(8,16),256,0,stream>>>(w1pl, w2T, nullptr, T12,   nullptr, nullptr, nullptr, nullptr, nullptr, nullptr, 1024, 2048);
  gemm_kernel<0,64><<<dim3(8,16),256,0,stream>>>(w3T,  T12, nullptr, WeffT, nullptr, nullptr, nullptr, nullptr, nullptr, nullptr, 1024, 1024);
  biasmv_kernel<<<1024,256,0,stream>>>(b1,   w2T, b2, tmpb, 2048);
  biasmv_kernel<<<1024,256,0,stream>>>(tmpb, w3T, b3, beff, 1024);

  // t=0: cur = x_in + x_in + emb[0]; hb = LN1(cur)
  add_ln_kernel<<<4096,256,0,stream>>>(x_in, x_in, emb, ln1w, ln1b, cur, hb);
  for(int t=0; t<8; t++){
    if(t > 0)
      add_ln_kernel<<<4096,256,0,stream>>>(cur, nullptr, nullptr, ln1w, ln1b, nullptr, hb);
    gemm_kernel<4,128><<<dim3(24,32),256,0,stream>>>(hb, wqkvT, nullptr, qb, kbuf, vtb, nullptr, nullptr, nullptr, nullptr, 3072, 1024);
    attn_kernel<<<dim3(64,8,2),256,0,stream>>>(qb, kbuf, vtb, pO, pL);
    attn_merge_kernel<<<dim3(64,16),256,0,stream>>>(pO, pL, attnb);
    gemm_kernel<2,64><<<dim3(8,64),256,0,stream>>>(attnb, fcT, x1, nullptr, nullptr, nullptr, fcb, cur, nullptr, nullptr, 1024, 1024);
    add_ln_kernel<<<4096,256,0,stream>>>(x1, nullptr, nullptr, ln2w, ln2b, nullptr, hb);
    if(t < 7)
      gemm_kernel<5,64><<<dim3(8,64),256,0,stream>>>(hb, WeffT, cur, nullptr, nullptr, nullptr, beff, x1, cur, emb + (t+1)*1024, 1024, 1024);
    else
      gemm_kernel<3,64><<<dim3(8,64),256,0,stream>>>(hb, WeffT, (float*)d_out, nullptr, nullptr, nullptr, beff, x1, nullptr, nullptr, 1024, 1024);
  }
}

// Round 9
// 1259.440 us; speedup vs baseline: 1.1273x; 1.1273x over previous
//
#include <hip/hip_runtime.h>
#include <hip/hip_bf16.h>
#include <math.h>

typedef __bf16 bf16;
typedef __bf16 bf16x8 __attribute__((ext_vector_type(8)));
typedef __bf16 bf16x4 __attribute__((ext_vector_type(4)));
typedef short  s16x4  __attribute__((ext_vector_type(4)));
typedef float  f32x4  __attribute__((ext_vector_type(4)));

#define MFMA32(a,b,c) __builtin_amdgcn_mfma_f32_16x16x32_bf16((a),(b),(c),0,0,0)
#define MFMA16(a,b,c) __builtin_amdgcn_mfma_f32_16x16x16bf16_1k((a),(b),(c),0,0,0)
#define EXP2F(x) __builtin_amdgcn_exp2f(x)
// async global->LDS, 16B per lane; LDS dest is wave-uniform base + lane*16 (m104/m108)
#define GLL16(gp, lp) __builtin_amdgcn_global_load_lds(\
    (const __attribute__((address_space(1))) void*)(gp), \
    (__attribute__((address_space(3))) void*)(lp), 16, 0, 0)

__device__ __forceinline__ float wave_sum(float v){
#pragma unroll
  for(int off=1; off<64; off<<=1) v += __shfl_xor(v, off);
  return v;
}

// ---------------- fused (add) + layernorm -> bf16 ----------------
__global__ __launch_bounds__(256) void add_ln_kernel(
    const float* __restrict__ xsrc, const float* __restrict__ addsrc,
    const float* __restrict__ emb,
    const float* __restrict__ gw, const float* __restrict__ gb,
    float* __restrict__ xout, bf16* __restrict__ hout)
{
  const int row = blockIdx.x;
  const int t = threadIdx.x;
  const size_t rbase = (size_t)row * 1024;
  float4 x = ((const float4*)(xsrc + rbase))[t];
  if(addsrc){
    float4 a = ((const float4*)(addsrc + rbase))[t];
    x.x += a.x; x.y += a.y; x.z += a.z; x.w += a.w;
  }
  if(emb){
    float4 e = ((const float4*)emb)[t];
    x.x += e.x; x.y += e.y; x.z += e.z; x.w += e.w;
  }
  if(xout) ((float4*)(xout + rbase))[t] = x;

  float s = x.x + x.y + x.z + x.w;
  float q = x.x*x.x + x.y*x.y + x.z*x.z + x.w*x.w;
  s = wave_sum(s); q = wave_sum(q);
  __shared__ float red[8];
  const int w = t >> 6;
  if((t & 63) == 0){ red[w] = s; red[4+w] = q; }
  __syncthreads();
  s = red[0]+red[1]+red[2]+red[3];
  q = red[4]+red[5]+red[6]+red[7];
  const float mean = s * (1.0f/1024.0f);
  const float var  = q * (1.0f/1024.0f) - mean*mean;
  const float inv  = rsqrtf(var + 1e-5f);

  float4 wv = ((const float4*)gw)[t];
  float4 bv = ((const float4*)gb)[t];
  bf16x4 hv;
  hv[0] = (bf16)((x.x - mean)*inv*wv.x + bv.x);
  hv[1] = (bf16)((x.y - mean)*inv*wv.y + bv.y);
  hv[2] = (bf16)((x.z - mean)*inv*wv.z + bv.z);
  hv[3] = (bf16)((x.w - mean)*inv*wv.w + bv.w);
  *(bf16x4*)(hout + rbase + t*4) = hv;
}

// ---------------- weight packing ----------------
__global__ __launch_bounds__(256) void pack_qkv3_kernel(
    const float* __restrict__ Wq, const float* __restrict__ Wk, const float* __restrict__ Wv,
    bf16* __restrict__ Wt)
{
  const int i = blockIdx.x*256 + threadIdx.x;       // 0..3M
  const int seg = i >> 20, j = i & 1048575;
  const float* W = (seg==0) ? Wq : (seg==1 ? Wk : Wv);
  const int n = j >> 10, d = j & 1023;
  const int h = n >> 6, kk = n & 63;
  Wt[i] = (bf16)W[h*65536 + d*64 + kk];
}
__global__ __launch_bounds__(256) void pack_t_kernel(const float* __restrict__ W, bf16* __restrict__ Wt, int Kd, int Nd){
  const int i = blockIdx.x*256 + threadIdx.x;
  const int n = i / Kd, k = i - n*Kd;
  Wt[i] = (bf16)W[(size_t)k*Nd + n];
}
__global__ __launch_bounds__(256) void pack_cast_kernel(const float* __restrict__ W, bf16* __restrict__ Wb){
  const int i = blockIdx.x*256 + threadIdx.x;
  Wb[i] = (bf16)W[i];
}
__global__ __launch_bounds__(256) void biasmv_kernel(const float* __restrict__ bin, const bf16* __restrict__ WT,
                                                     const float* __restrict__ badd, float* __restrict__ out, int Kd){
  const int n = blockIdx.x, t = threadIdx.x;
  float acc = 0.f;
  for(int k=t; k<Kd; k+=256) acc += bin[k]*(float)WT[(size_t)n*Kd + k];
  acc = wave_sum(acc);
  __shared__ float red[4];
  if((t&63)==0) red[t>>6] = acc;
  __syncthreads();
  if(t==0) out[n] = red[0]+red[1]+red[2]+red[3] + badd[n];
}

// ---------------- bf16 MFMA GEMM, BK=64:  C[M,N] = A[M,K] * Bt[N,K]^T ----------------
// EPI: 0 plain->bf16 ; 1 +bias->bf16 ; 2 res+acc+bias->f32 ; 3 res+gelu(acc+bias)->f32 ;
//      4 qkv split (q prescaled by log2e/32, v transposed per-head) ;
//      5 cur' = res2 + res + gelu(acc+bias) + embn[col]
template<int EPI, int BLKM>
__global__ __launch_bounds__(256,2) void gemm_kernel(
    const bf16* __restrict__ A, const bf16* __restrict__ Bt,
    float* __restrict__ outf, bf16* __restrict__ outb,
    bf16* __restrict__ o2, bf16* __restrict__ o3,
    const float* __restrict__ bias, const float* __restrict__ res,
    const float* __restrict__ res2, const float* __restrict__ embn,
    int N, int K)
{
  constexpr int RM = BLKM/32;
  constexpr int HM = BLKM/2;
  constexpr int AISS = BLKM/32;
  __shared__ __align__(16) bf16 As[BLKM*64];
  __shared__ __align__(16) bf16 Bs[128*64];
  const int tid = threadIdx.x, w = tid>>6, lane = tid&63;
  const int quad = lane>>4, l16 = lane&15;
  const int wm = w&1, wn = w>>1;
  const int tn = blockIdx.x, tm = blockIdx.y;

  const int srow = lane>>3;
  const int sch  = (lane&7) ^ srow;
  const bf16* Ag = A  + (size_t)(tm*BLKM + w*8 + srow)*K + sch*8;
  const bf16* Bg = Bt + (size_t)(tn*128  + w*8 + srow)*K + sch*8;

  f32x4 acc[RM][4] = {};

  for(int k0 = 0; k0 < K; k0 += 64){
#pragma unroll
    for(int i=0;i<AISS;i++) GLL16(Ag + (size_t)(i*32)*K, As + (w*8 + i*32)*64);
#pragma unroll
    for(int i=0;i<4;i++)    GLL16(Bg + (size_t)(i*32)*K, Bs + (w*8 + i*32)*64);
    Ag += 64; Bg += 64;
    __syncthreads();
    bf16x8 af[RM][2], bfr[4][2];
#pragma unroll
    for(int r=0;r<RM;r++){
      const int row = wm*HM + r*16 + l16;
      const bf16* rp = As + row*64;
#pragma unroll
      for(int kc=0;kc<2;kc++)
        af[r][kc] = *(const bf16x8*)(rp + ((kc*4+quad) ^ (row&7))*8);
    }
#pragma unroll
    for(int c=0;c<4;c++){
      const int row = wn*64 + c*16 + l16;
      const bf16* rp = Bs + row*64;
#pragma unroll
      for(int kc=0;kc<2;kc++)
        bfr[c][kc] = *(const bf16x8*)(rp + ((kc*4+quad) ^ (row&7))*8);
    }
#pragma unroll
    for(int kc=0;kc<2;kc++)
#pragma unroll
      for(int r=0;r<RM;r++)
#pragma unroll
        for(int c=0;c<4;c++)
          acc[r][c] = MFMA32(af[r][kc], bfr[c][kc], acc[r][c]);
    __syncthreads();
  }

  // C/D: col = lane&15, row = quad*4 + reg
#pragma unroll
  for(int r=0;r<RM;r++){
    const int grow0 = tm*BLKM + wm*HM + r*16 + quad*4;
#pragma unroll
    for(int c=0;c<4;c++){
      const int gcol = tn*128 + wn*64 + c*16 + l16;
      float bv = 0.0f;
      if constexpr (EPI>=1 && EPI!=4) bv = bias[gcol];
      if constexpr (EPI==4){
        const int seg = gcol >> 10;          // wave-uniform
        if(seg < 2){
          bf16* op = (seg==0) ? outb : o2;
          // q: fold 1024^-0.5 * log2(e) so attention uses raw v_exp_f32 (exp2)
          const float qs = (seg==0) ? 0.045084439f : 1.0f;
          const int col = gcol & 1023;
#pragma unroll
          for(int g=0; g<4; g++)
            op[(size_t)(grow0+g)*1024 + col] = (bf16)(acc[r][c][g]*qs);
        } else {
          const int col0 = gcol & 1023, hh = col0>>6, kk = col0&63;
          const int btok = grow0>>10, t0 = grow0&1023;
          bf16x4 pv;
#pragma unroll
          for(int g=0; g<4; g++) pv[g] = (bf16)acc[r][c][g];
          *(bf16x4*)(o3 + ((size_t)(btok*16+hh)*64 + kk)*1024 + t0) = pv;
        }
      } else {
        const float ev = (EPI==5) ? embn[gcol] : 0.0f;
#pragma unroll
        for(int g=0; g<4; g++){
          const float vv = acc[r][c][g] + bv;
          const size_t idx = (size_t)(grow0+g)*N + gcol;
          if constexpr (EPI<=1){
            outb[idx] = (bf16)vv;
          } else if constexpr (EPI==2){
            outf[idx] = res[idx] + vv;
          } else if constexpr (EPI==3){
            const float gel = 0.5f*vv*(1.0f + erff(vv*0.70710678118654752f));
            outf[idx] = res[idx] + gel;
          } else {
            const float gel = 0.5f*vv*(1.0f + erff(vv*0.70710678118654752f));
            outf[idx] = res[idx] + gel + res2[idx] + ev;
          }
        }
      }
    }
  }
}

// ---------------- fused causal attention (R7 structure + exp2 + deferred l-reduce) ----------------
// grid (64 bh, 8 p): XCD = bh%8 -> all 8 p-blocks of a bh share one XCD L2.
// paired q-tiles (A=p, B=15-p): 17 tile-iterations per block (perfect balance).
// No online max: Q prescaled by log2e/32 -> raw v_exp_f32; masked keys -> 0.
// l-reduction deferred: per-lane partials across all iters, 2 shuffles once at epilogue.
// S^T = K*Q^T; P^T (C-layout) == B-operand of 16x16x16 -> O^T = V^T*P^T from registers.
constexpr int LDK = 72;   // padded rows: 144B stride -> 2-way bank alias only (free)

__global__ __launch_bounds__(256) void attn_kernel(
    const bf16* __restrict__ Q, const bf16* __restrict__ Km,
    const bf16* __restrict__ Vt, bf16* __restrict__ O)
{
  __shared__ __align__(16) bf16 Ks[2][64*LDK];   // [buf][key][hd]
  __shared__ __align__(16) bf16 Vs[2][64*LDK];   // [buf][hd][key]
  const int p  = blockIdx.y;          // 0..7
  const int qtA = p, qtB = 15 - p;
  const int bh = blockIdx.x;          // 0..63 -> XCD = bh%8
  const int b = bh >> 4, h = bh & 15;
  const int tid = threadIdx.x;
  const int w = tid>>6, lane = tid&63, quad = lane>>4, l16 = lane&15;
  const size_t qbase = (size_t)b*1024*1024 + (size_t)h*64;
  const size_t vbase = (size_t)(bh*64)*1024;
  const int qrowA0 = qtA*64 + w*16, qrowB0 = qtB*64 + w*16;
  const int myrowA = qrowA0 + l16,  myrowB = qrowB0 + l16;

  // Q as B-frag: n=l16 (qrow), k=quad*8+j (hd). Q prescaled by log2e/32.
  const bf16* qpA = Q + qbase + (size_t)myrowA*1024 + quad*8;
  const bf16* qpB = Q + qbase + (size_t)myrowB*1024 + quad*8;
  bf16x8 bqA0 = *(const bf16x8*)qpA, bqA1 = *(const bf16x8*)(qpA + 32);
  bf16x8 bqB0 = *(const bf16x8*)qpB, bqB1 = *(const bf16x8*)(qpB + 32);

  f32x4 oA[4] = {}, oB[4] = {};     // O^T: hd = d*16+quad*4+g, qrow = l16
  float lA = 0.f, lB = 0.f;         // per-lane partial denominators (reduced at epilogue)
  const f32x4 zf = {0.f,0.f,0.f,0.f};

  // staging map: thread -> K row r0/r0+32 (keys), V row r0/r0+32 (hd), 16B chunk c0
  const int r0 = tid>>3, c0 = (tid&7)*8;
  const bf16* kg = Km + qbase + c0;
  const bf16* vg = Vt + vbase + (size_t)r0*1024 + c0;

  // prologue: stage kb=0 into buffer 0
  {
    const bf16* kgp = kg + (size_t)r0*1024;
    bf16x8 a0 = *(const bf16x8*)kgp;
    bf16x8 a1 = *(const bf16x8*)(kgp + (size_t)32*1024);
    bf16x8 v0 = *(const bf16x8*)vg;
    bf16x8 v1 = *(const bf16x8*)(vg + (size_t)32*1024);
    *(bf16x8*)(Ks[0] + r0*LDK + c0)      = a0;
    *(bf16x8*)(Ks[0] + (r0+32)*LDK + c0) = a1;
    *(bf16x8*)(Vs[0] + r0*LDK + c0)      = v0;
    *(bf16x8*)(Vs[0] + (r0+32)*LDK + c0) = v1;
  }

  for(int kb = 0; kb <= qtB; kb++){
    const int cur = kb & 1;
    const bool pf = (kb < qtB);
    __syncthreads();                       // staging of kb visible; kb-1 reads done

    // prefetch kb+1 into registers (consumed by ds_write AFTER compute -> latency hidden)
    bf16x8 nk0, nk1, nv0, nv1;
    if(pf){
      const bf16* kgp = kg + (size_t)((kb+1)*64 + r0)*1024;
      nk0 = *(const bf16x8*)kgp;
      nk1 = *(const bf16x8*)(kgp + (size_t)32*1024);
      const bf16* vgp = vg + (kb+1)*64;
      nv0 = *(const bf16x8*)vgp;
      nv1 = *(const bf16x8*)(vgp + (size_t)32*1024);
    }

    const bool diagA = (kb == qtA), diagB = (kb == qtB);
    const int ncA = (kb < qtA) ? 4 : (diagA ? (w+1) : 0);
    const int ncB = diagB ? (w+1) : 4;

    const bf16* ksb = Ks[cur];
    const bf16* vsb = Vs[cur];

    // S^T: A = K (m=key), B = Q (n=qrow); shared K-frags feed both tiles
    f32x4 sA[4], sB[4];
#pragma unroll
    for(int c=0;c<4;c++){
      if(c >= ncB) continue;
      bf16x8 ak0 = *(const bf16x8*)(ksb + (c*16+l16)*LDK + quad*8);
      bf16x8 ak1 = *(const bf16x8*)(ksb + (c*16+l16)*LDK + 32 + quad*8);
      sB[c] = MFMA32(ak0, bqB0, zf);
      sB[c] = MFMA32(ak1, bqB1, sB[c]);
      if(c < ncA){
        sA[c] = MFMA32(ak0, bqA0, zf);
        sA[c] = MFMA32(ak1, bqA1, sA[c]);
      }
    }

    // softmax numerators (no max subtraction; masked -> 0; per-lane l partials)
    s16x4 pB[4], pA[4];
#pragma unroll
    for(int c=0;c<4;c++){
      if(c >= ncB) continue;
      bf16x4 pb;
#pragma unroll
      for(int g=0;g<4;g++){
        const int key = kb*64 + c*16 + quad*4 + g;
        const float e = (diagB && key > myrowB) ? 0.f : EXP2F(sB[c][g]);
        lB += e; pb[g] = (bf16)e;
      }
      pB[c] = __builtin_bit_cast(s16x4, pb);
    }
#pragma unroll
    for(int c=0;c<4;c++){
      if(c >= ncA) continue;
      bf16x4 pb;
#pragma unroll
      for(int g=0;g<4;g++){
        const int key = kb*64 + c*16 + quad*4 + g;
        const float e = (diagA && key > myrowA) ? 0.f : EXP2F(sA[c][g]);
        lA += e; pb[g] = (bf16)e;
      }
      pA[c] = __builtin_bit_cast(s16x4, pb);
    }

    // PV: O^T += V^T * P^T (shared V-frags)
#pragma unroll
    for(int c=0;c<4;c++){
      if(c >= ncB) continue;
#pragma unroll
      for(int d=0;d<4;d++){
        bf16x4 av = *(const bf16x4*)(vsb + (d*16+l16)*LDK + c*16 + quad*4);
        const s16x4 avs = __builtin_bit_cast(s16x4, av);
        oB[d] = MFMA16(avs, pB[c], oB[d]);
        if(c < ncA) oA[d] = MFMA16(avs, pA[c], oA[d]);
      }
    }

    // write prefetched kb+1 into the other buffer
    if(pf){
      bf16* kd = Ks[cur^1]; bf16* vd = Vs[cur^1];
      *(bf16x8*)(kd + r0*LDK + c0)      = nk0;
      *(bf16x8*)(kd + (r0+32)*LDK + c0) = nk1;
      *(bf16x8*)(vd + r0*LDK + c0)      = nv0;
      *(bf16x8*)(vd + (r0+32)*LDK + c0) = nv1;
    }
  }

  // final l-reduction: combine the 4 key-quads per qrow (deferred from the loop)
  lA += __shfl_xor(lA, 16); lA += __shfl_xor(lA, 32);
  lB += __shfl_xor(lB, 16); lB += __shfl_xor(lB, 32);

  // epilogue: O^T -> LDS bounce -> coalesced stores (per-wave regions)
  __syncthreads();
  {
    bf16* ot = Ks[0] + w*(16*LDK);
    const float inv = 1.0f / lA;
#pragma unroll
    for(int d=0;d<4;d++)
#pragma unroll
      for(int g=0;g<4;g++)
        ot[l16*LDK + d*16 + quad*4 + g] = (bf16)(oA[d][g]*inv);
#pragma unroll
    for(int p2=0;p2<2;p2++){
      const int qr = (lane>>3) + 8*p2, hd0 = (lane&7)*8;
      bf16x8 val = *(const bf16x8*)(ot + qr*LDK + hd0);
      *(bf16x8*)(O + qbase + (size_t)(qrowA0+qr)*1024 + hd0) = val;
    }
  }
  {
    bf16* ot = Ks[1] + w*(16*LDK);
    const float inv = 1.0f / lB;
#pragma unroll
    for(int d=0;d<4;d++)
#pragma unroll
      for(int g=0;g<4;g++)
        ot[l16*LDK + d*16 + quad*4 + g] = (bf16)(oB[d][g]*inv);
#pragma unroll
    for(int p2=0;p2<2;p2++){
      const int qr = (lane>>3) + 8*p2, hd0 = (lane&7)*8;
      bf16x8 val = *(const bf16x8*)(ot + qr*LDK + hd0);
      *(bf16x8*)(O + qbase + (size_t)(qrowB0+qr)*1024 + hd0) = val;
    }
  }
}

// ---------------- launch ----------------
extern "C" void kernel_launch(void* const* d_in, const int* in_sizes, int n_in,
                              void* d_out, int out_size, void* d_ws, size_t ws_size,
                              hipStream_t stream)
{
  const float* x_in = (const float*)d_in[0];
  const float* emb  = (const float*)d_in[1];
  const float* Wq   = (const float*)d_in[2];
  const float* Wk   = (const float*)d_in[3];
  const float* Wv   = (const float*)d_in[4];
  const float* fcw  = (const float*)d_in[5];
  const float* fcb  = (const float*)d_in[6];
  const float* ln1w = (const float*)d_in[7];
  const float* ln1b = (const float*)d_in[8];
  const float* ln2w = (const float*)d_in[9];
  const float* ln2b = (const float*)d_in[10];
  const float* w1   = (const float*)d_in[11];
  const float* b1   = (const float*)d_in[12];
  const float* w2   = (const float*)d_in[13];
  const float* b2   = (const float*)d_in[14];
  const float* w3   = (const float*)d_in[15];
  const float* b3   = (const float*)d_in[16];

  char* ws = (char*)d_ws;
  const size_t MB = 1024*1024;
  float* cur    = (float*)(ws + 0);
  float* x1     = (float*)(ws + 16*MB);
  bf16*  hb     = (bf16*)(ws + 48*MB);
  bf16*  attnb  = (bf16*)(ws + 56*MB);
  bf16*  qb     = (bf16*)(ws + 64*MB);
  bf16*  kbuf   = (bf16*)(ws + 72*MB);
  bf16*  vtb    = (bf16*)(ws + 80*MB);    // V^T per-head: [(b*16+h)*64+hd][t]
  bf16*  w1pl   = (bf16*)(ws + 88*MB);
  bf16*  T12    = (bf16*)(ws + 92*MB);
  bf16*  wqkvT  = (bf16*)(ws + 96*MB);
  bf16*  fcT    = (bf16*)(ws + 102*MB);
  bf16*  w2T    = (bf16*)(ws + 104*MB);
  bf16*  w3T    = (bf16*)(ws + 108*MB);
  bf16*  WeffT  = (bf16*)(ws + 110*MB);
  float* tmpb   = (float*)(ws + 112*MB);
  float* beff   = (float*)(ws + 112*MB + 8192);

  pack_qkv3_kernel<<<12288,256,0,stream>>>(Wq, Wk, Wv, wqkvT);
  pack_t_kernel<<<4096,256,0,stream>>>(fcw, fcT, 1024, 1024);
  pack_t_kernel<<<8192,256,0,stream>>>(w2,  w2T, 2048, 1024);
  pack_t_kernel<<<4096,256,0,stream>>>(w3,  w3T, 1024, 1024);
  pack_cast_kernel<<<8192,256,0,stream>>>(w1, w1pl);
  gemm_kernel<0,64><<<dim3(8,16),256,0,stream>>>(w1pl, w2T, nullptr, T12,   nullptr, nullptr, nullptr, nullptr, nullptr, nullptr, 1024, 2048);
  gemm_kernel<0,64><<<dim3(8,16),256,0,stream>>>(w3T,  T12, nullptr, WeffT, nullptr, nullptr, nullptr, nullptr, nullptr, nullptr, 1024, 1024);
  biasmv_kernel<<<1024,256,0,stream>>>(b1,   w2T, b2, tmpb, 2048);
  biasmv_kernel<<<1024,256,0,stream>>>(tmpb, w3T, b3, beff, 1024);

  // t=0: cur = x_in + x_in + emb[0]; hb = LN1(cur)
  add_ln_kernel<<<4096,256,0,stream>>>(x_in, x_in, emb, ln1w, ln1b, cur, hb);
  for(int t=0; t<8; t++){
    if(t > 0)
      add_ln_kernel<<<4096,256,0,stream>>>(cur, nullptr, nullptr, ln1w, ln1b, nullptr, hb);
    gemm_kernel<4,128><<<dim3(24,32),256,0,stream>>>(hb, wqkvT, nullptr, qb, kbuf, vtb, nullptr, nullptr, nullptr, nullptr, 3072, 1024);
    attn_kernel<<<dim3(64,8),256,0,stream>>>(qb, kbuf, vtb, attnb);
    gemm_kernel<2,64><<<dim3(8,64),256,0,stream>>>(attnb, fcT, x1, nullptr, nullptr, nullptr, fcb, cur, nullptr, nullptr, 1024, 1024);
    add_ln_kernel<<<4096,256,0,stream>>>(x1, nullptr, nullptr, ln2w, ln2b, nullptr, hb);
    if(t < 7)
      gemm_kernel<5,64><<<dim3(8,64),256,0,stream>>>(hb, WeffT, cur, nullptr, nullptr, nullptr, beff, x1, cur, emb + (t+1)*1024, 1024, 1024);
    else
      gemm_kernel<3,64><<<dim3(8,64),256,0,stream>>>(hb, WeffT, (float*)d_out, nullptr, nullptr, nullptr, beff, x1, nullptr, nullptr, 1024, 1024);
  }
}